// Round 1
// baseline (79.858 us; speedup 1.0000x reference)
//
#include <hip/hip_runtime.h>
#include <hip/hip_bf16.h>
#include <stdint.h>

#define B_    64
#define N_    512
#define M2    52      // M_PARAM + 2
#define MLPH  128
#define NACT  512
#define FC_IN 2204    // 512 + 512*3 + 52*3
#define KQ    551     // FC_IN / 4
#define NEG   0.2f
#define NW    16      // mask words per target (512/32)

__device__ __forceinline__ float lrelu(float v){ return v > 0.f ? v : NEG * v; }

// ---------------- Kernel P: adj -> transposed bitmask ----------------
// maskT[b][j][w] bit k set iff adj[b][i=32w+k][j] > 0.
// Grid: 64 b * 8 j-tiles = 512 blocks, 256 threads.
__global__ __launch_bounds__(256) void kmask(const float* __restrict__ adj,
                                             uint32_t* __restrict__ maskT){
  int bx = blockIdx.x;
  int b  = bx >> 3;
  int j0 = (bx & 7) * 64;
  int t  = threadIdx.x;
  int j4 = t & 15;     // 4-column group within the 64-col tile
  int w  = t >> 4;     // word index 0..15 (source rows 32w..32w+31)
  const float* basef = adj + ((size_t)(b * N_ + (w << 5))) * N_ + (j0 + (j4 << 2));
  uint32_t w0 = 0, w1 = 0, w2 = 0, w3 = 0;
#pragma unroll
  for (int k = 0; k < 32; ++k) {
    float4 v = *(const float4*)(basef + (size_t)k * N_);
    w0 |= (v.x > 0.f ? 1u : 0u) << k;
    w1 |= (v.y > 0.f ? 1u : 0u) << k;
    w2 |= (v.z > 0.f ? 1u : 0u) << k;
    w3 |= (v.w > 0.f ? 1u : 0u) << k;
  }
  uint32_t* dst = maskT + ((size_t)(b * N_ + j0 + (j4 << 2))) * NW + w;
  dst[0]      = w0;
  dst[NW]     = w1;
  dst[2 * NW] = w2;
  dst[3 * NW] = w3;
}

// ---------------- Kernel B: GAT layer 1 (x -> g1), heads=2, relu ----------------
// Grid: 64 b * 2 halves = 128 blocks, 256 threads (1 target each).
__global__ __launch_bounds__(256) void kgat1(const float* __restrict__ x,
                                             const float* __restrict__ W1,
                                             const float* __restrict__ as1,
                                             const float* __restrict__ ad1,
                                             const float* __restrict__ b1,
                                             const uint32_t* __restrict__ maskT,
                                             float* __restrict__ g1){
  __shared__ float node[N_][8];   // h0..h5, es0, es1
  int b = blockIdx.x >> 1, half = blockIdx.x & 1, t = threadIdx.x;

  float w[18];
#pragma unroll
  for (int i = 0; i < 18; ++i) w[i] = W1[i];
  float av0[3], av1[3];
#pragma unroll
  for (int d = 0; d < 3; ++d) { av0[d] = as1[d]; av1[d] = as1[3 + d]; }

  for (int i = t; i < N_; i += 256) {
    float xv[3];
#pragma unroll
    for (int d = 0; d < 3; ++d) xv[d] = x[((size_t)(b * N_ + i)) * 3 + d];
    float h[6];
#pragma unroll
    for (int c = 0; c < 6; ++c) h[c] = xv[0] * w[c] + xv[1] * w[6 + c] + xv[2] * w[12 + c];
#pragma unroll
    for (int c = 0; c < 6; ++c) node[i][c] = h[c];
    node[i][6] = h[0] * av0[0] + h[1] * av0[1] + h[2] * av0[2];
    node[i][7] = h[3] * av1[0] + h[4] * av1[1] + h[5] * av1[2];
  }
  __syncthreads();

  int j = half * 256 + t;
  float ed0 = node[j][0] * ad1[0] + node[j][1] * ad1[1] + node[j][2] * ad1[2];
  float ed1 = node[j][3] * ad1[3] + node[j][4] * ad1[4] + node[j][5] * ad1[5];

  uint32_t wv[16];
  const uint4* m4 = (const uint4*)(maskT + (size_t)(b * N_ + j) * NW);
#pragma unroll
  for (int q = 0; q < 4; ++q) {
    uint4 mv = m4[q];
    wv[4 * q + 0] = mv.x; wv[4 * q + 1] = mv.y; wv[4 * q + 2] = mv.z; wv[4 * q + 3] = mv.w;
  }
  int selfw = j >> 5; uint32_t selfb = 1u << (j & 31);

  float den0 = 0.f, den1 = 0.f, acc[6] = {0.f, 0.f, 0.f, 0.f, 0.f, 0.f};
#pragma unroll
  for (int ww = 0; ww < 16; ++ww) {
    uint32_t bits = wv[ww];
    if (ww == selfw) bits |= selfb;
    while (bits) {
      int k = __ffs(bits) - 1;
      bits &= bits - 1;
      int i = (ww << 5) + k;
      float e0 = __expf(lrelu(node[i][6] + ed0));
      float e1 = __expf(lrelu(node[i][7] + ed1));
      den0 += e0; den1 += e1;
      acc[0] += e0 * node[i][0]; acc[1] += e0 * node[i][1]; acc[2] += e0 * node[i][2];
      acc[3] += e1 * node[i][3]; acc[4] += e1 * node[i][4]; acc[5] += e1 * node[i][5];
    }
  }
  float r0 = 1.f / den0, r1 = 1.f / den1;
  float* gout = g1 + (size_t)(b * N_ + j) * 6;
  gout[0] = fmaxf(acc[0] * r0 + b1[0], 0.f);
  gout[1] = fmaxf(acc[1] * r0 + b1[1], 0.f);
  gout[2] = fmaxf(acc[2] * r0 + b1[2], 0.f);
  gout[3] = fmaxf(acc[3] * r1 + b1[3], 0.f);
  gout[4] = fmaxf(acc[4] * r1 + b1[4], 0.f);
  gout[5] = fmaxf(acc[5] * r1 + b1[5], 0.f);
}

// ---------------- Kernel D: GAT layer 2 (g1 -> g2), heads=1, no relu ----------------
__global__ __launch_bounds__(256) void kgat2(const float* __restrict__ g1,
                                             const float* __restrict__ W2,
                                             const float* __restrict__ as2,
                                             const float* __restrict__ ad2,
                                             const float* __restrict__ b2,
                                             const uint32_t* __restrict__ maskT,
                                             float* __restrict__ g2){
  __shared__ float node[N_][4];   // h0,h1,h2,es
  int b = blockIdx.x >> 1, half = blockIdx.x & 1, t = threadIdx.x;

  float w[18];
#pragma unroll
  for (int i = 0; i < 18; ++i) w[i] = W2[i];
  float av[3] = {as2[0], as2[1], as2[2]};

  for (int i = t; i < N_; i += 256) {
    float gv[6];
#pragma unroll
    for (int c = 0; c < 6; ++c) gv[c] = g1[((size_t)(b * N_ + i)) * 6 + c];
    float h[3];
#pragma unroll
    for (int c = 0; c < 3; ++c)
      h[c] = gv[0]*w[c] + gv[1]*w[3+c] + gv[2]*w[6+c] + gv[3]*w[9+c] + gv[4]*w[12+c] + gv[5]*w[15+c];
    node[i][0] = h[0]; node[i][1] = h[1]; node[i][2] = h[2];
    node[i][3] = h[0]*av[0] + h[1]*av[1] + h[2]*av[2];
  }
  __syncthreads();

  int j = half * 256 + t;
  float ed = node[j][0]*ad2[0] + node[j][1]*ad2[1] + node[j][2]*ad2[2];

  uint32_t wv[16];
  const uint4* m4 = (const uint4*)(maskT + (size_t)(b * N_ + j) * NW);
#pragma unroll
  for (int q = 0; q < 4; ++q) {
    uint4 mv = m4[q];
    wv[4 * q + 0] = mv.x; wv[4 * q + 1] = mv.y; wv[4 * q + 2] = mv.z; wv[4 * q + 3] = mv.w;
  }
  int selfw = j >> 5; uint32_t selfb = 1u << (j & 31);

  float den = 0.f, a0 = 0.f, a1 = 0.f, a2 = 0.f;
#pragma unroll
  for (int ww = 0; ww < 16; ++ww) {
    uint32_t bits = wv[ww];
    if (ww == selfw) bits |= selfb;
    while (bits) {
      int k = __ffs(bits) - 1;
      bits &= bits - 1;
      int i = (ww << 5) + k;
      float e = __expf(lrelu(node[i][3] + ed));
      den += e;
      a0 += e * node[i][0]; a1 += e * node[i][1]; a2 += e * node[i][2];
    }
  }
  float r = 1.f / den;
  float* gout = g2 + (size_t)(b * N_ + j) * 3;
  gout[0] = a0 * r + b2[0];
  gout[1] = a1 * r + b2[1];
  gout[2] = a2 * r + b2[2];
}

// ---------------- Kernel E: fused MLP (feat -> 128 -> 512) ----------------
// Grid: 64 blocks (1 per batch), 512 threads.
__global__ __launch_bounds__(512) void kmlp(const float* __restrict__ idx,
                                            const float* __restrict__ y,
                                            const float* __restrict__ g2,
                                            const float* __restrict__ Wf1,
                                            const float* __restrict__ bf1,
                                            const float* __restrict__ Wf2,
                                            const float* __restrict__ bf2,
                                            float* __restrict__ out){
  __shared__ float feat[FC_IN];
  __shared__ float part[4 * MLPH];
  __shared__ float hid[MLPH];
  int b = blockIdx.x, t = threadIdx.x;

  feat[t] = idx[(size_t)b * N_ + t];
  for (int e = t; e < N_ * 3; e += 512) feat[N_ + e] = g2[(size_t)b * N_ * 3 + e];
  if (t < M2 * 3) feat[N_ + N_ * 3 + t] = y[(size_t)b * M2 * 3 + t];
  __syncthreads();

  int u = t & 127, q = t >> 7;
  {
    int k0 = q * KQ, k1 = k0 + KQ;
    float p = 0.f;
    for (int k = k0; k < k1; ++k) p += feat[k] * Wf1[(size_t)k * MLPH + u];
    part[q * MLPH + u] = p;
  }
  __syncthreads();
  if (t < MLPH) {
    float h = part[t] + part[MLPH + t] + part[2 * MLPH + t] + part[3 * MLPH + t] + bf1[t];
    hid[t] = fmaxf(h, 0.f);
  }
  __syncthreads();

  float acc = bf2[t];
#pragma unroll 8
  for (int k = 0; k < MLPH; ++k) acc += hid[k] * Wf2[(size_t)k * NACT + t];
  out[(size_t)b * NACT + t] = acc;
}

extern "C" void kernel_launch(void* const* d_in, const int* in_sizes, int n_in,
                              void* d_out, int out_size, void* d_ws, size_t ws_size,
                              hipStream_t stream) {
  const float* idx = (const float*)d_in[0];
  const float* x   = (const float*)d_in[1];
  const float* y   = (const float*)d_in[2];
  const float* adj = (const float*)d_in[3];
  const float* W1  = (const float*)d_in[4];
  const float* as1 = (const float*)d_in[5];
  const float* ad1 = (const float*)d_in[6];
  const float* b1  = (const float*)d_in[7];
  const float* W2  = (const float*)d_in[8];
  const float* as2 = (const float*)d_in[9];
  const float* ad2 = (const float*)d_in[10];
  const float* b2  = (const float*)d_in[11];
  const float* Wf1 = (const float*)d_in[12];
  const float* bf1 = (const float*)d_in[13];
  const float* Wf2 = (const float*)d_in[14];
  const float* bf2 = (const float*)d_in[15];
  float* out = (float*)d_out;

  uint8_t* ws = (uint8_t*)d_ws;
  uint32_t* maskT = (uint32_t*)ws;                       // 64*512*16*4 = 2 MB
  float* g1 = (float*)(ws + 2097152);                    // 64*512*6*4  = 768 KB
  float* g2 = (float*)(ws + 2097152 + 786432);           // 64*512*3*4  = 384 KB

  hipLaunchKernelGGL(kmask, dim3(512), dim3(256), 0, stream, adj, maskT);
  hipLaunchKernelGGL(kgat1, dim3(128), dim3(256), 0, stream, x, W1, as1, ad1, b1, maskT, g1);
  hipLaunchKernelGGL(kgat2, dim3(128), dim3(256), 0, stream, g1, W2, as2, ad2, b2, maskT, g2);
  hipLaunchKernelGGL(kmlp,  dim3(64),  dim3(512), 0, stream, idx, y, g2, Wf1, bf1, Wf2, bf2, out);
}

// Round 2
// 45.911 us; speedup vs baseline: 1.7394x; 1.7394x over previous
//
#include <hip/hip_runtime.h>
#include <hip/hip_bf16.h>
#include <stdint.h>

#define B_    64
#define N_    512
#define M2    52      // M_PARAM + 2
#define MLPH  128
#define NACT  512
#define FC_IN 2204    // 512 + 512*3 + 52*3
#define NCH   18      // ceil(2204/128) feat k-chunks
#define NEG   0.2f
#define NW    16      // mask words per target (512/32)

__device__ __forceinline__ float lrelu(float v){ return v > 0.f ? v : NEG * v; }

// ---------------- Kernel P: adj -> transposed bitmask ----------------
// maskT[b][j][w] bit k set iff adj[b][i=32w+k][j] > 0.
// Grid: 64 b * 8 j-tiles = 512 blocks, 512 threads (k-split halves, LDS OR).
__global__ __launch_bounds__(512) void kmask(const float* __restrict__ adj,
                                             uint32_t* __restrict__ maskT){
  __shared__ uint32_t lm[2][64][16];   // 8 KB
  int bx = blockIdx.x;
  int b  = bx >> 3;
  int j0 = (bx & 7) * 64;
  int t  = threadIdx.x;
  int j4 = t & 15;          // 4-column group within the 64-col tile
  int w  = (t >> 4) & 15;   // word index 0..15 (source rows 32w..32w+31)
  int kh = t >> 8;          // k-half: rows 32w+16kh .. +15
  const float* basef = adj + ((size_t)(b * N_ + (w << 5) + (kh << 4))) * N_ + (j0 + (j4 << 2));
  uint32_t m0 = 0, m1 = 0, m2 = 0, m3 = 0;
#pragma unroll
  for (int k = 0; k < 16; ++k) {
    float4 v = *(const float4*)(basef + (size_t)k * N_);
    m0 |= (v.x > 0.f ? 1u : 0u) << k;
    m1 |= (v.y > 0.f ? 1u : 0u) << k;
    m2 |= (v.z > 0.f ? 1u : 0u) << k;
    m3 |= (v.w > 0.f ? 1u : 0u) << k;
  }
  int sh = kh << 4;
  lm[kh][(j4 << 2) + 0][w] = m0 << sh;
  lm[kh][(j4 << 2) + 1][w] = m1 << sh;
  lm[kh][(j4 << 2) + 2][w] = m2 << sh;
  lm[kh][(j4 << 2) + 3][w] = m3 << sh;
  __syncthreads();
  for (int e = t; e < 64 * 16; e += 512) {
    int w2 = e & 15, jj = e >> 4;
    maskT[((size_t)(b * N_ + j0 + jj)) * NW + w2] = lm[0][jj][w2] | lm[1][jj][w2];
  }
}

// ---------------- Kernel B: GAT layer 1 (x -> g1), heads=2, relu ----------------
// Grid: 64 b * 2 halves = 128 blocks, 256 threads (1 target each).
__global__ __launch_bounds__(256) void kgat1(const float* __restrict__ x,
                                             const float* __restrict__ W1,
                                             const float* __restrict__ as1,
                                             const float* __restrict__ ad1,
                                             const float* __restrict__ b1,
                                             const uint32_t* __restrict__ maskT,
                                             float* __restrict__ g1){
  __shared__ float node[N_][8];   // h0..h5, es0, es1
  int b = blockIdx.x >> 1, half = blockIdx.x & 1, t = threadIdx.x;

  float w[18];
#pragma unroll
  for (int i = 0; i < 18; ++i) w[i] = W1[i];
  float av0[3], av1[3];
#pragma unroll
  for (int d = 0; d < 3; ++d) { av0[d] = as1[d]; av1[d] = as1[3 + d]; }

  for (int i = t; i < N_; i += 256) {
    float xv[3];
#pragma unroll
    for (int d = 0; d < 3; ++d) xv[d] = x[((size_t)(b * N_ + i)) * 3 + d];
    float h[6];
#pragma unroll
    for (int c = 0; c < 6; ++c) h[c] = xv[0] * w[c] + xv[1] * w[6 + c] + xv[2] * w[12 + c];
#pragma unroll
    for (int c = 0; c < 6; ++c) node[i][c] = h[c];
    node[i][6] = h[0] * av0[0] + h[1] * av0[1] + h[2] * av0[2];
    node[i][7] = h[3] * av1[0] + h[4] * av1[1] + h[5] * av1[2];
  }
  __syncthreads();

  int j = half * 256 + t;
  float ed0 = node[j][0] * ad1[0] + node[j][1] * ad1[1] + node[j][2] * ad1[2];
  float ed1 = node[j][3] * ad1[3] + node[j][4] * ad1[4] + node[j][5] * ad1[5];

  uint32_t wv[16];
  const uint4* m4 = (const uint4*)(maskT + (size_t)(b * N_ + j) * NW);
#pragma unroll
  for (int q = 0; q < 4; ++q) {
    uint4 mv = m4[q];
    wv[4 * q + 0] = mv.x; wv[4 * q + 1] = mv.y; wv[4 * q + 2] = mv.z; wv[4 * q + 3] = mv.w;
  }
  int selfw = j >> 5; uint32_t selfb = 1u << (j & 31);

  float den0 = 0.f, den1 = 0.f, acc[6] = {0.f, 0.f, 0.f, 0.f, 0.f, 0.f};
#pragma unroll
  for (int ww = 0; ww < 16; ++ww) {
    uint32_t bits = wv[ww];
    if (ww == selfw) bits |= selfb;
    while (bits) {
      int k = __ffs(bits) - 1;
      bits &= bits - 1;
      int i = (ww << 5) + k;
      float e0 = __expf(lrelu(node[i][6] + ed0));
      float e1 = __expf(lrelu(node[i][7] + ed1));
      den0 += e0; den1 += e1;
      acc[0] += e0 * node[i][0]; acc[1] += e0 * node[i][1]; acc[2] += e0 * node[i][2];
      acc[3] += e1 * node[i][3]; acc[4] += e1 * node[i][4]; acc[5] += e1 * node[i][5];
    }
  }
  float r0 = 1.f / den0, r1 = 1.f / den1;
  float* gout = g1 + (size_t)(b * N_ + j) * 6;
  gout[0] = fmaxf(acc[0] * r0 + b1[0], 0.f);
  gout[1] = fmaxf(acc[1] * r0 + b1[1], 0.f);
  gout[2] = fmaxf(acc[2] * r0 + b1[2], 0.f);
  gout[3] = fmaxf(acc[3] * r1 + b1[3], 0.f);
  gout[4] = fmaxf(acc[4] * r1 + b1[4], 0.f);
  gout[5] = fmaxf(acc[5] * r1 + b1[5], 0.f);
}

// ---------------- Kernel D: GAT layer 2 (g1 -> g2), heads=1, no relu ----------------
__global__ __launch_bounds__(256) void kgat2(const float* __restrict__ g1,
                                             const float* __restrict__ W2,
                                             const float* __restrict__ as2,
                                             const float* __restrict__ ad2,
                                             const float* __restrict__ b2,
                                             const uint32_t* __restrict__ maskT,
                                             float* __restrict__ g2){
  __shared__ float node[N_][4];   // h0,h1,h2,es
  int b = blockIdx.x >> 1, half = blockIdx.x & 1, t = threadIdx.x;

  float w[18];
#pragma unroll
  for (int i = 0; i < 18; ++i) w[i] = W2[i];
  float av[3] = {as2[0], as2[1], as2[2]};

  for (int i = t; i < N_; i += 256) {
    float gv[6];
#pragma unroll
    for (int c = 0; c < 6; ++c) gv[c] = g1[((size_t)(b * N_ + i)) * 6 + c];
    float h[3];
#pragma unroll
    for (int c = 0; c < 3; ++c)
      h[c] = gv[0]*w[c] + gv[1]*w[3+c] + gv[2]*w[6+c] + gv[3]*w[9+c] + gv[4]*w[12+c] + gv[5]*w[15+c];
    node[i][0] = h[0]; node[i][1] = h[1]; node[i][2] = h[2];
    node[i][3] = h[0]*av[0] + h[1]*av[1] + h[2]*av[2];
  }
  __syncthreads();

  int j = half * 256 + t;
  float ed = node[j][0]*ad2[0] + node[j][1]*ad2[1] + node[j][2]*ad2[2];

  uint32_t wv[16];
  const uint4* m4 = (const uint4*)(maskT + (size_t)(b * N_ + j) * NW);
#pragma unroll
  for (int q = 0; q < 4; ++q) {
    uint4 mv = m4[q];
    wv[4 * q + 0] = mv.x; wv[4 * q + 1] = mv.y; wv[4 * q + 2] = mv.z; wv[4 * q + 3] = mv.w;
  }
  int selfw = j >> 5; uint32_t selfb = 1u << (j & 31);

  float den = 0.f, a0 = 0.f, a1 = 0.f, a2 = 0.f;
#pragma unroll
  for (int ww = 0; ww < 16; ++ww) {
    uint32_t bits = wv[ww];
    if (ww == selfw) bits |= selfb;
    while (bits) {
      int k = __ffs(bits) - 1;
      bits &= bits - 1;
      int i = (ww << 5) + k;
      float e = __expf(lrelu(node[i][3] + ed));
      den += e;
      a0 += e * node[i][0]; a1 += e * node[i][1]; a2 += e * node[i][2];
    }
  }
  float r = 1.f / den;
  float* gout = g2 + (size_t)(b * N_ + j) * 3;
  gout[0] = a0 * r + b2[0];
  gout[1] = a1 * r + b2[1];
  gout[2] = a2 * r + b2[2];
}

// ---------------- Kernel E1: MLP layer 1, split-K partials ----------------
// Grid: (18 chunks, 64 b), 128 threads. partial[b][c][u].
__global__ __launch_bounds__(128) void kmlp1(const float* __restrict__ idx,
                                             const float* __restrict__ y,
                                             const float* __restrict__ g2,
                                             const float* __restrict__ Wf1,
                                             float* __restrict__ partial){
  __shared__ float fs[128];
  int c = blockIdx.x, b = blockIdx.y, t = threadIdx.x;
  int k = c * 128 + t;
  float v = 0.f;
  if (k < FC_IN) {
    if (k < N_)            v = idx[(size_t)b * N_ + k];
    else if (k < N_ * 4)   v = g2[(size_t)b * (N_ * 3) + (k - N_)];
    else                   v = y[(size_t)b * (M2 * 3) + (k - N_ * 4)];
  }
  fs[t] = v;
  __syncthreads();
  int klen = min(128, FC_IN - c * 128);
  const float* wp = Wf1 + (size_t)(c * 128) * MLPH + t;
  float p = 0.f;
#pragma unroll 8
  for (int kk = 0; kk < klen; ++kk) p += fs[kk] * wp[(size_t)kk * MLPH];
  partial[((size_t)b * NCH + c) * MLPH + t] = p;
}

// ---------------- Kernel E2: reduce + relu + MLP layer 2 ----------------
// Grid: (4 out-quarters, 64 b), 128 threads.
__global__ __launch_bounds__(128) void kmlp2(const float* __restrict__ partial,
                                             const float* __restrict__ bf1,
                                             const float* __restrict__ Wf2,
                                             const float* __restrict__ bf2,
                                             float* __restrict__ out){
  __shared__ float hid[MLPH];
  int q = blockIdx.x, b = blockIdx.y, t = threadIdx.x;
  float s = bf1[t];
  const float* pp = partial + (size_t)b * NCH * MLPH + t;
#pragma unroll
  for (int c = 0; c < NCH; ++c) s += pp[c * MLPH];
  hid[t] = fmaxf(s, 0.f);
  __syncthreads();
  int o = q * 128 + t;
  float acc = bf2[o];
  const float* wp = Wf2 + o;
#pragma unroll 8
  for (int k = 0; k < MLPH; ++k) acc += hid[k] * wp[(size_t)k * NACT];
  out[(size_t)b * NACT + o] = acc;
}

extern "C" void kernel_launch(void* const* d_in, const int* in_sizes, int n_in,
                              void* d_out, int out_size, void* d_ws, size_t ws_size,
                              hipStream_t stream) {
  const float* idx = (const float*)d_in[0];
  const float* x   = (const float*)d_in[1];
  const float* y   = (const float*)d_in[2];
  const float* adj = (const float*)d_in[3];
  const float* W1  = (const float*)d_in[4];
  const float* as1 = (const float*)d_in[5];
  const float* ad1 = (const float*)d_in[6];
  const float* b1  = (const float*)d_in[7];
  const float* W2  = (const float*)d_in[8];
  const float* as2 = (const float*)d_in[9];
  const float* ad2 = (const float*)d_in[10];
  const float* b2  = (const float*)d_in[11];
  const float* Wf1 = (const float*)d_in[12];
  const float* bf1 = (const float*)d_in[13];
  const float* Wf2 = (const float*)d_in[14];
  const float* bf2 = (const float*)d_in[15];
  float* out = (float*)d_out;

  uint8_t* ws = (uint8_t*)d_ws;
  uint32_t* maskT  = (uint32_t*)ws;                                  // 2 MB
  float* g1        = (float*)(ws + 2097152);                         // 768 KB
  float* g2        = (float*)(ws + 2097152 + 786432);                // 384 KB
  float* partial   = (float*)(ws + 2097152 + 786432 + 393216);       // 576 KB

  hipLaunchKernelGGL(kmask, dim3(512), dim3(512), 0, stream, adj, maskT);
  hipLaunchKernelGGL(kgat1, dim3(128), dim3(256), 0, stream, x, W1, as1, ad1, b1, maskT, g1);
  hipLaunchKernelGGL(kgat2, dim3(128), dim3(256), 0, stream, g1, W2, as2, ad2, b2, maskT, g2);
  hipLaunchKernelGGL(kmlp1, dim3(NCH, B_), dim3(128), 0, stream, idx, y, g2, Wf1, partial);
  hipLaunchKernelGGL(kmlp2, dim3(4, B_),   dim3(128), 0, stream, partial, bf1, Wf2, bf2, out);
}

// Round 3
// 38.438 us; speedup vs baseline: 2.0776x; 1.1944x over previous
//
#include <hip/hip_runtime.h>
#include <hip/hip_bf16.h>
#include <stdint.h>

#define B_    64
#define N_    512
#define M2    52      // M_PARAM + 2
#define MLPH  128
#define NACT  512
#define FC_IN 2204    // 512 + 512*3 + 52*3
#define NCH   18      // ceil(2204/128) feat k-chunks
#define NEG   0.2f
#define NW    16      // mask words per target (512/32)

__device__ __forceinline__ float lrelu(float v){ return v > 0.f ? v : NEG * v; }

// ---------------- Kernel 1: adj -> bitmask + GAT layer 1 + transform 2 ----------------
// Grid: (8 j-tiles, 64 b), 512 threads.
// Outputs: maskT[b][j][16] (for layer 2), node2[b][j][4] = {h2_0,h2_1,h2_2,es2}.
__global__ __launch_bounds__(512) void kfuse1(const float* __restrict__ adj,
                                              const float* __restrict__ x,
                                              const float* __restrict__ W1,
                                              const float* __restrict__ as1,
                                              const float* __restrict__ ad1,
                                              const float* __restrict__ b1,
                                              const float* __restrict__ W2,
                                              const float* __restrict__ as2,
                                              uint32_t* __restrict__ maskT,
                                              float* __restrict__ node2){
  __shared__ uint32_t lm[2][64][16];   // 8 KB
  __shared__ float node[N_][8];        // 16 KB: h0..h5, es0, es1
  int b  = blockIdx.y;
  int j0 = blockIdx.x * 64;
  int t  = threadIdx.x;

  // ---- Phase A: adj column bits for this 64-target tile ----
  {
    int j4 = t & 15;          // 4-col group
    int w  = (t >> 4) & 15;   // word (source rows 32w..)
    int kh = t >> 8;          // k-half
    const float* basef = adj + ((size_t)(b * N_ + (w << 5) + (kh << 4))) * N_ + (j0 + (j4 << 2));
    uint32_t m0 = 0, m1 = 0, m2 = 0, m3 = 0;
#pragma unroll
    for (int k = 0; k < 16; ++k) {
      float4 v = *(const float4*)(basef + (size_t)k * N_);
      m0 |= (v.x > 0.f ? 1u : 0u) << k;
      m1 |= (v.y > 0.f ? 1u : 0u) << k;
      m2 |= (v.z > 0.f ? 1u : 0u) << k;
      m3 |= (v.w > 0.f ? 1u : 0u) << k;
    }
    int sh = kh << 4;
    lm[kh][(j4 << 2) + 0][w] = m0 << sh;
    lm[kh][(j4 << 2) + 1][w] = m1 << sh;
    lm[kh][(j4 << 2) + 2][w] = m2 << sh;
    lm[kh][(j4 << 2) + 3][w] = m3 << sh;
  }

  // ---- Phase A': layer-1 node transform (one node per thread) ----
  {
    float xv0 = x[((size_t)(b * N_ + t)) * 3 + 0];
    float xv1 = x[((size_t)(b * N_ + t)) * 3 + 1];
    float xv2 = x[((size_t)(b * N_ + t)) * 3 + 2];
    float h[6];
#pragma unroll
    for (int c = 0; c < 6; ++c) h[c] = xv0 * W1[c] + xv1 * W1[6 + c] + xv2 * W1[12 + c];
#pragma unroll
    for (int c = 0; c < 6; ++c) node[t][c] = h[c];
    node[t][6] = h[0] * as1[0] + h[1] * as1[1] + h[2] * as1[2];
    node[t][7] = h[3] * as1[3] + h[4] * as1[4] + h[5] * as1[5];
  }
  __syncthreads();

  // ---- Phase B: aggregate, 16 lanes per target, 2 passes over 64 targets ----
  int w  = t & 15;
  int tg = t >> 4;
  float ad10 = ad1[0], ad11 = ad1[1], ad12 = ad1[2];
  float ad13 = ad1[3], ad14 = ad1[4], ad15 = ad1[5];
  float b10 = b1[0], b11 = b1[1], b12 = b1[2], b13 = b1[3], b14 = b1[4], b15 = b1[5];
  float as20 = as2[0], as21 = as2[1], as22 = as2[2];

#pragma unroll
  for (int p = 0; p < 2; ++p) {
    int jj = tg + p * 32;
    int j  = j0 + jj;
    uint32_t bits = lm[0][jj][w] | lm[1][jj][w];
    maskT[((size_t)(b * N_ + j)) * NW + w] = bits;
    if ((j >> 5) == w) bits |= 1u << (j & 31);

    float ed0 = node[j][0] * ad10 + node[j][1] * ad11 + node[j][2] * ad12;
    float ed1 = node[j][3] * ad13 + node[j][4] * ad14 + node[j][5] * ad15;

    float den0 = 0.f, den1 = 0.f;
    float a0 = 0.f, a1 = 0.f, a2 = 0.f, a3 = 0.f, a4 = 0.f, a5 = 0.f;
    while (bits) {
      int k = __ffs(bits) - 1;
      bits &= bits - 1;
      int i = (w << 5) + k;
      float e0 = __expf(lrelu(node[i][6] + ed0));
      float e1 = __expf(lrelu(node[i][7] + ed1));
      den0 += e0; den1 += e1;
      a0 += e0 * node[i][0]; a1 += e0 * node[i][1]; a2 += e0 * node[i][2];
      a3 += e1 * node[i][3]; a4 += e1 * node[i][4]; a5 += e1 * node[i][5];
    }
#pragma unroll
    for (int m = 1; m < 16; m <<= 1) {
      den0 += __shfl_xor(den0, m); den1 += __shfl_xor(den1, m);
      a0 += __shfl_xor(a0, m); a1 += __shfl_xor(a1, m); a2 += __shfl_xor(a2, m);
      a3 += __shfl_xor(a3, m); a4 += __shfl_xor(a4, m); a5 += __shfl_xor(a5, m);
    }
    float r0 = 1.f / den0, r1 = 1.f / den1;
    float g0 = fmaxf(a0 * r0 + b10, 0.f);
    float g1v = fmaxf(a1 * r0 + b11, 0.f);
    float g2v = fmaxf(a2 * r0 + b12, 0.f);
    float g3 = fmaxf(a3 * r1 + b13, 0.f);
    float g4 = fmaxf(a4 * r1 + b14, 0.f);
    float g5 = fmaxf(a5 * r1 + b15, 0.f);
    // layer-2 transform: h2[c] = sum_r g[r] * W2[r*3+c]
    float h20 = g0*W2[0] + g1v*W2[3] + g2v*W2[6] + g3*W2[9]  + g4*W2[12] + g5*W2[15];
    float h21 = g0*W2[1] + g1v*W2[4] + g2v*W2[7] + g3*W2[10] + g4*W2[13] + g5*W2[16];
    float h22 = g0*W2[2] + g1v*W2[5] + g2v*W2[8] + g3*W2[11] + g4*W2[14] + g5*W2[17];
    float es2 = h20 * as20 + h21 * as21 + h22 * as22;
    if (w < 4) {
      float outv = (w == 0) ? h20 : (w == 1) ? h21 : (w == 2) ? h22 : es2;
      node2[((size_t)(b * N_ + j)) * 4 + w] = outv;
    }
  }
}

// ---------------- Kernel 2: GAT layer 2 aggregation ----------------
// Grid: (32 tiles, 64 b), 256 threads = 16 targets x 16 lanes.
__global__ __launch_bounds__(256) void kagg2(const float* __restrict__ node2,
                                             const float* __restrict__ ad2,
                                             const float* __restrict__ b2,
                                             const uint32_t* __restrict__ maskT,
                                             float* __restrict__ g2){
  __shared__ float sn[N_][4];   // 8 KB
  int b = blockIdx.y, tile = blockIdx.x, t = threadIdx.x;

  const float4* src = (const float4*)(node2 + (size_t)b * N_ * 4);
  for (int e = t; e < N_; e += 256) {
    float4 v = src[e];
    sn[e][0] = v.x; sn[e][1] = v.y; sn[e][2] = v.z; sn[e][3] = v.w;
  }
  __syncthreads();

  int w = t & 15, tg = t >> 4;
  int j = tile * 16 + tg;
  float ad20 = ad2[0], ad21 = ad2[1], ad22 = ad2[2];

  uint32_t bits = maskT[((size_t)(b * N_ + j)) * NW + w];
  if ((j >> 5) == w) bits |= 1u << (j & 31);

  float ed = sn[j][0] * ad20 + sn[j][1] * ad21 + sn[j][2] * ad22;
  float den = 0.f, a0 = 0.f, a1 = 0.f, a2 = 0.f;
  while (bits) {
    int k = __ffs(bits) - 1;
    bits &= bits - 1;
    int i = (w << 5) + k;
    float e = __expf(lrelu(sn[i][3] + ed));
    den += e;
    a0 += e * sn[i][0]; a1 += e * sn[i][1]; a2 += e * sn[i][2];
  }
#pragma unroll
  for (int m = 1; m < 16; m <<= 1) {
    den += __shfl_xor(den, m);
    a0 += __shfl_xor(a0, m); a1 += __shfl_xor(a1, m); a2 += __shfl_xor(a2, m);
  }
  if (w < 3) {
    float r = 1.f / den;
    float v = (w == 0 ? a0 : w == 1 ? a1 : a2) * r + b2[w];
    g2[((size_t)(b * N_ + j)) * 3 + w] = v;
  }
}

// ---------------- Kernel 3: MLP layer 1, split-K partials ----------------
// Grid: (18 chunks, 64 b), 128 threads. partial[b][c][u].
__global__ __launch_bounds__(128) void kmlp1(const float* __restrict__ idx,
                                             const float* __restrict__ y,
                                             const float* __restrict__ g2,
                                             const float* __restrict__ Wf1,
                                             float* __restrict__ partial){
  __shared__ float fs[128];
  int c = blockIdx.x, b = blockIdx.y, t = threadIdx.x;
  int k = c * 128 + t;
  float v = 0.f;
  if (k < FC_IN) {
    if (k < N_)            v = idx[(size_t)b * N_ + k];
    else if (k < N_ * 4)   v = g2[(size_t)b * (N_ * 3) + (k - N_)];
    else                   v = y[(size_t)b * (M2 * 3) + (k - N_ * 4)];
  }
  fs[t] = v;
  __syncthreads();
  int klen = min(128, FC_IN - c * 128);
  const float* wp = Wf1 + (size_t)(c * 128) * MLPH + t;
  float p = 0.f;
#pragma unroll 8
  for (int kk = 0; kk < klen; ++kk) p += fs[kk] * wp[(size_t)kk * MLPH];
  partial[((size_t)b * NCH + c) * MLPH + t] = p;
}

// ---------------- Kernel 4: reduce + relu + MLP layer 2 ----------------
// Grid: (4 out-quarters, 64 b), 128 threads.
__global__ __launch_bounds__(128) void kmlp2(const float* __restrict__ partial,
                                             const float* __restrict__ bf1,
                                             const float* __restrict__ Wf2,
                                             const float* __restrict__ bf2,
                                             float* __restrict__ out){
  __shared__ float hid[MLPH];
  int q = blockIdx.x, b = blockIdx.y, t = threadIdx.x;
  float s = bf1[t];
  const float* pp = partial + (size_t)b * NCH * MLPH + t;
#pragma unroll
  for (int c = 0; c < NCH; ++c) s += pp[c * MLPH];
  hid[t] = fmaxf(s, 0.f);
  __syncthreads();
  int o = q * 128 + t;
  float acc = bf2[o];
  const float* wp = Wf2 + o;
#pragma unroll 8
  for (int k = 0; k < MLPH; ++k) acc += hid[k] * wp[(size_t)k * NACT];
  out[(size_t)b * NACT + o] = acc;
}

extern "C" void kernel_launch(void* const* d_in, const int* in_sizes, int n_in,
                              void* d_out, int out_size, void* d_ws, size_t ws_size,
                              hipStream_t stream) {
  const float* idx = (const float*)d_in[0];
  const float* x   = (const float*)d_in[1];
  const float* y   = (const float*)d_in[2];
  const float* adj = (const float*)d_in[3];
  const float* W1  = (const float*)d_in[4];
  const float* as1 = (const float*)d_in[5];
  const float* ad1 = (const float*)d_in[6];
  const float* b1  = (const float*)d_in[7];
  const float* W2  = (const float*)d_in[8];
  const float* as2 = (const float*)d_in[9];
  const float* ad2 = (const float*)d_in[10];
  const float* b2  = (const float*)d_in[11];
  const float* Wf1 = (const float*)d_in[12];
  const float* bf1 = (const float*)d_in[13];
  const float* Wf2 = (const float*)d_in[14];
  const float* bf2 = (const float*)d_in[15];
  float* out = (float*)d_out;

  uint8_t* ws = (uint8_t*)d_ws;
  uint32_t* maskT = (uint32_t*)ws;                             // 2 MB
  float* node2    = (float*)(ws + 2097152);                    // 512 KB
  float* g2       = (float*)(ws + 2097152 + 524288);           // 384 KB
  float* partial  = (float*)(ws + 2097152 + 524288 + 393216);  // 576 KB

  hipLaunchKernelGGL(kfuse1, dim3(8, B_),   dim3(512), 0, stream,
                     adj, x, W1, as1, ad1, b1, W2, as2, maskT, node2);
  hipLaunchKernelGGL(kagg2,  dim3(32, B_),  dim3(256), 0, stream,
                     node2, ad2, b2, maskT, g2);
  hipLaunchKernelGGL(kmlp1,  dim3(NCH, B_), dim3(128), 0, stream, idx, y, g2, Wf1, partial);
  hipLaunchKernelGGL(kmlp2,  dim3(4, B_),   dim3(128), 0, stream, partial, bf1, Wf2, bf2, out);
}